// Round 4
// baseline (1941.034 us; speedup 1.0000x reference)
//
#include <hip/hip_runtime.h>

typedef _Float16 half8 __attribute__((ext_vector_type(8)));
typedef _Float16 half4 __attribute__((ext_vector_type(4)));
typedef float floatx4 __attribute__((ext_vector_type(4)));

__device__ __forceinline__ float fast_rcp(float x) { return __builtin_amdgcn_rcpf(x); }
__device__ __forceinline__ float fast_sigmoid(float x) {
  return fast_rcp(1.f + __expf(-x));
}
__device__ __forceinline__ float fast_tanh(float x) {
  return 1.f - 2.f * fast_rcp(1.f + __expf(2.f * x));
}

// ---------------- prep: fp16 fragment-ordered weights + bias sums ----------------
// B-frag layout for mfma_f32_16x16x32_f16: lane L, reg j holds
// W[n = ntile*16 + (L&15)][k = ktile*32 + (L>>4)*8 + j].
// Buffer: [ktile][ntile(32)][lane(64)][8 f16]. Verified correct across all rounds.
__global__ void prep_kernel(const float* __restrict__ wih0, const float* __restrict__ whh0,
                            const float* __restrict__ bih0, const float* __restrict__ bhh0,
                            const float* __restrict__ wih1, const float* __restrict__ whh1,
                            const float* __restrict__ bih1, const float* __restrict__ bhh1,
                            _Float16* __restrict__ w0f, _Float16* __restrict__ w1f,
                            float* __restrict__ bias0, float* __restrict__ bias1)
{
  int stride = gridDim.x * blockDim.x;
  int idx0 = blockIdx.x * blockDim.x + threadIdx.x;
  const int N0 = 6*32*64*8;      // layer0: K=192 (x 64 | h 128)
  const int N1 = 8*32*64*8;      // layer1: K=256 (h1 128 | h 128)
  for (int e = idx0; e < N0 + N1 + 1024; e += stride) {
    if (e < N0) {
      int j = e & 7; int le = e >> 3; int lane = le & 63; int frag = le >> 6;
      int kt = frag >> 5, ntile = frag & 31;
      int n = ntile*16 + (lane & 15);
      int kk = kt*32 + ((lane >> 4) << 3) + j;
      float v = (kk < 64) ? wih0[n*64 + kk] : whh0[n*128 + (kk - 64)];
      w0f[e] = (_Float16)v;
    } else if (e < N0 + N1) {
      int e2 = e - N0;
      int j = e2 & 7; int le = e2 >> 3; int lane = le & 63; int frag = le >> 6;
      int kt = frag >> 5, ntile = frag & 31;
      int n = ntile*16 + (lane & 15);
      int kk = kt*32 + ((lane >> 4) << 3) + j;
      float v = (kk < 128) ? wih1[n*128 + kk] : whh1[n*128 + (kk - 128)];
      w1f[e2] = (_Float16)v;
    } else {
      int i = e - (N0 + N1);
      if (i < 512) bias0[i] = bih0[i] + bhh0[i];
      else         bias1[i - 512] = bih1[i - 512] + bhh1[i - 512];
    }
  }
}

// ---------------- layer 0: 1 row/block, 512 blocks, 4 waves ----------------
// 2 blocks/CU = two INDEPENDENT barrier domains -> when one block stalls at its
// per-step barrier, the co-resident block issues (m114 co-scheduling).
// Per wave: 2 column-tiles (en0 = w*16+li, en1 = en0+64), 32 MFMAs/step.
// M=16 batching: input projection for 16 steps at once, every 16 phases.
// Keeps round-3's wins: T14 stage split (issue at t%16==0, LDS-write at t%16==8)
// and pre-activation fold in the epilogue.
__global__ __launch_bounds__(256, 2) void lstm_l0(const float* __restrict__ x,
    const _Float16* __restrict__ w0f, const float* __restrict__ bias0,
    _Float16* __restrict__ h1out)
{
  const int tid = threadIdx.x;
  const int lane = tid & 63;
  const int w = tid >> 6;                 // 0..3
  const int li = lane & 15;
  const int r = blockIdx.x;

  __shared__ float preLDS[2][8192];       // 64 KB: [slot][(m*128+en)*4+g], m=0..15
  __shared__ half8 aF[2][128];            // x A-frags, 2 ktiles, 4 KB
  __shared__ half8 hA[2][16];             // compact recurrent frags (512 B)
  __shared__ _Float16 hist[16][128];      // h ring (4 KB)

  if (tid < 128) ((int*)hA)[tid] = 0;

  // resident recurrent weights: kt 2..5, 4 g, 2 ct = 32 frags = 128 AGPRs
  half8 bfr[4][4][2];
#pragma unroll
  for (int kt = 0; kt < 4; ++kt)
#pragma unroll
    for (int g = 0; g < 4; ++g)
#pragma unroll
      for (int ct = 0; ct < 2; ++ct) {
        int frag = (kt+2)*32 + g*8 + w + 4*ct;
        bfr[kt][g][ct] = *reinterpret_cast<const half8*>(w0f + (size_t)(frag*64 + lane)*8);
        asm volatile("" : "+a"(bfr[kt][g][ct]));
      }
  float b_v[4][2];
#pragma unroll
  for (int g = 0; g < 4; ++g) {
    b_v[g][0] = bias0[g*128 + w*16 + li];
    b_v[g][1] = bias0[g*128 + (w+4)*16 + li];
  }

  // staging: thread -> (step-in-batch, col-quad); A[m=sdt][k=scq..scq+3]
  const int sdt = tid >> 4, scq = (tid & 15) * 4;
  const int sidx = ((scq>>5)*64 + sdt + (((scq&31)>>3)<<4))*8 + (scq & 7);

  const bool arow = (li == 0);
  const int kgrp = lane >> 4;
  const int en0 = w*16 + li;
  const int en1 = en0 + 64;
  const int eoff0 = ((en0>>5)*4 + ((en0&31)>>3))*8 + (en0&7);
  const int eoff1 = ((en1>>5)*4 + ((en1&31)>>3))*8 + (en1&7);
  float cst0 = 0.f, cst1 = 0.f;

  // prologue: stage batches 0 and 1
  {
    float4 v0 = *reinterpret_cast<const float4*>(x + ((size_t)r*512 + sdt)*64 + scq);
    float4 v1 = *reinterpret_cast<const float4*>(x + ((size_t)r*512 + 16 + sdt)*64 + scq);
    half4 h0 = {(_Float16)v0.x, (_Float16)v0.y, (_Float16)v0.z, (_Float16)v0.w};
    half4 h1v = {(_Float16)v1.x, (_Float16)v1.y, (_Float16)v1.z, (_Float16)v1.w};
    *reinterpret_cast<half4*>(((_Float16*)aF[0]) + sidx) = h0;
    *reinterpret_cast<half4*>(((_Float16*)aF[1]) + sidx) = h1v;
  }
  __syncthreads();
  {                                        // project batch 0 -> preLDS[0]
    const _Float16* wp = w0f; asm volatile("" : "+v"(wp));
    floatx4 accP[4][2];
#pragma unroll
    for (int g = 0; g < 4; ++g)
#pragma unroll
      for (int ct = 0; ct < 2; ++ct) { float bb = b_v[g][ct]; accP[g][ct] = (floatx4){bb,bb,bb,bb}; }
#pragma unroll
    for (int kt = 0; kt < 2; ++kt) {
      half8 af = aF[0][kt*64 + lane];
#pragma unroll
      for (int g = 0; g < 4; ++g)
#pragma unroll
        for (int ct = 0; ct < 2; ++ct) {
          half8 wfr = *reinterpret_cast<const half8*>(wp + (size_t)((kt*32 + g*8 + w + 4*ct)*64 + lane)*8);
          accP[g][ct] = __builtin_amdgcn_mfma_f32_16x16x32_f16(af, wfr, accP[g][ct], 0, 0, 0);
        }
    }
#pragma unroll
    for (int reg = 0; reg < 4; ++reg) {
      int m = (lane>>4)*4 + reg;
      floatx4 pv0 = (floatx4){accP[0][0][reg], accP[1][0][reg], accP[2][0][reg], accP[3][0][reg]};
      floatx4 pv1 = (floatx4){accP[0][1][reg], accP[1][1][reg], accP[2][1][reg], accP[3][1][reg]};
      *reinterpret_cast<floatx4*>(&preLDS[0][(m*128 + en0)*4]) = pv0;
      *reinterpret_cast<floatx4*>(&preLDS[0][(m*128 + en1)*4]) = pv1;
    }
  }

  half8 a0 = {}, a1 = {}, a2 = {}, a3 = {};
  float4 sv;

  for (int t = 0; t < 512; ++t) {
    const int bb = t >> 4;
    __syncthreads();
    if ((t & 15) == 0) {
      if (bb < 30) {                       // issue stage load for batch bb+2
        sv = *reinterpret_cast<const float4*>(x + ((size_t)r*512 + (bb+2)*16 + sdt)*64 + scq);
      }
      if (bb < 31) {                       // project batch bb+1 -> preLDS[(bb+1)&1]
        int slot = (bb+1) & 1;
        const _Float16* wp = w0f; asm volatile("" : "+v"(wp));
        floatx4 accP[4][2];
#pragma unroll
        for (int g = 0; g < 4; ++g)
#pragma unroll
          for (int ct = 0; ct < 2; ++ct) { float bv = b_v[g][ct]; accP[g][ct] = (floatx4){bv,bv,bv,bv}; }
#pragma unroll
        for (int kt = 0; kt < 2; ++kt) {
          half8 af = aF[slot][kt*64 + lane];
#pragma unroll
          for (int g = 0; g < 4; ++g)
#pragma unroll
            for (int ct = 0; ct < 2; ++ct) {
              half8 wfr = *reinterpret_cast<const half8*>(wp + (size_t)((kt*32 + g*8 + w + 4*ct)*64 + lane)*8);
              accP[g][ct] = __builtin_amdgcn_mfma_f32_16x16x32_f16(af, wfr, accP[g][ct], 0, 0, 0);
            }
        }
#pragma unroll
        for (int reg = 0; reg < 4; ++reg) {
          int m = (lane>>4)*4 + reg;
          floatx4 pv0 = (floatx4){accP[0][0][reg], accP[1][0][reg], accP[2][0][reg], accP[3][0][reg]};
          floatx4 pv1 = (floatx4){accP[0][1][reg], accP[1][1][reg], accP[2][1][reg], accP[3][1][reg]};
          *reinterpret_cast<floatx4*>(&preLDS[slot][(m*128 + en0)*4]) = pv0;
          *reinterpret_cast<floatx4*>(&preLDS[slot][(m*128 + en1)*4]) = pv1;
        }
      }
    }
    if ((t & 15) == 8 && bb < 30) {        // write stashed batch bb+2 -> aF[bb&1]
      half4 hv = {(_Float16)sv.x, (_Float16)sv.y, (_Float16)sv.z, (_Float16)sv.w};
      *reinterpret_cast<half4*>(((_Float16*)aF[bb&1]) + sidx) = hv;
    }
    if ((t & 7) == 0 && t >= 8) {          // coalesced flush of steps t-8..t-1
      int tbase = t - 8;
      int fdt = tid >> 5, n = (tid & 31) * 4;
      half4 v = *reinterpret_cast<const half4*>(&hist[(tbase + fdt) & 15][n]);
      *reinterpret_cast<half4*>(h1out + ((size_t)r*512 + tbase + fdt)*128 + n) = v;
    }

    // pre-activation read (folded in epilogue -> off the MFMA critical path)
    floatx4 p40 = (floatx4){0.f,0.f,0.f,0.f}, p41 = (floatx4){0.f,0.f,0.f,0.f};
    if (lane < 16) {
      int m = t & 15;
      p40 = *reinterpret_cast<const floatx4*>(&preLDS[bb & 1][(m*128 + en0)*4]);
      p41 = *reinterpret_cast<const floatx4*>(&preLDS[bb & 1][(m*128 + en1)*4]);
    }
    floatx4 acc[4][2];
#pragma unroll
    for (int g = 0; g < 4; ++g) {
      acc[g][0] = (floatx4){0.f,0.f,0.f,0.f};
      acc[g][1] = (floatx4){0.f,0.f,0.f,0.f};
    }

    const int cur = t & 1;
    if (arow) {
      a0 = hA[cur][ 0 + kgrp];
      a1 = hA[cur][ 4 + kgrp];
      a2 = hA[cur][ 8 + kgrp];
      a3 = hA[cur][12 + kgrp];
    }
#pragma unroll
    for (int g = 0; g < 4; ++g) {
      acc[g][0] = __builtin_amdgcn_mfma_f32_16x16x32_f16(a0, bfr[0][g][0], acc[g][0], 0, 0, 0);
      acc[g][1] = __builtin_amdgcn_mfma_f32_16x16x32_f16(a0, bfr[0][g][1], acc[g][1], 0, 0, 0);
    }
#pragma unroll
    for (int g = 0; g < 4; ++g) {
      acc[g][0] = __builtin_amdgcn_mfma_f32_16x16x32_f16(a1, bfr[1][g][0], acc[g][0], 0, 0, 0);
      acc[g][1] = __builtin_amdgcn_mfma_f32_16x16x32_f16(a1, bfr[1][g][1], acc[g][1], 0, 0, 0);
    }
#pragma unroll
    for (int g = 0; g < 4; ++g) {
      acc[g][0] = __builtin_amdgcn_mfma_f32_16x16x32_f16(a2, bfr[2][g][0], acc[g][0], 0, 0, 0);
      acc[g][1] = __builtin_amdgcn_mfma_f32_16x16x32_f16(a2, bfr[2][g][1], acc[g][1], 0, 0, 0);
    }
#pragma unroll
    for (int g = 0; g < 4; ++g) {
      acc[g][0] = __builtin_amdgcn_mfma_f32_16x16x32_f16(a3, bfr[3][g][0], acc[g][0], 0, 0, 0);
      acc[g][1] = __builtin_amdgcn_mfma_f32_16x16x32_f16(a3, bfr[3][g][1], acc[g][1], 0, 0, 0);
    }

    if (lane < 16) {
      float i0 = fast_sigmoid(p40[0] + acc[0][0][0]);
      float f0 = fast_sigmoid(p40[1] + acc[1][0][0]);
      float g0 = fast_tanh  (p40[2] + acc[2][0][0]);
      float o0 = fast_sigmoid(p40[3] + acc[3][0][0]);
      float i1 = fast_sigmoid(p41[0] + acc[0][1][0]);
      float f1 = fast_sigmoid(p41[1] + acc[1][1][0]);
      float g1 = fast_tanh  (p41[2] + acc[2][1][0]);
      float o1 = fast_sigmoid(p41[3] + acc[3][1][0]);
      cst0 = f0*cst0 + i0*g0;
      cst1 = f1*cst1 + i1*g1;
      float h0v = o0*fast_tanh(cst0);
      float h1v = o1*fast_tanh(cst1);
      _Float16 hh0 = (_Float16)h0v;
      _Float16 hh1 = (_Float16)h1v;
      ((_Float16*)hA[cur^1])[eoff0] = hh0;
      ((_Float16*)hA[cur^1])[eoff1] = hh1;
      hist[t & 15][en0] = hh0;
      hist[t & 15][en1] = hh1;
    }
  }
  __syncthreads();
  {                                        // final flush: steps 504..511
    int tbase = 504;
    int fdt = tid >> 5, n = (tid & 31) * 4;
    half4 v = *reinterpret_cast<const half4*>(&hist[(tbase + fdt) & 15][n]);
    *reinterpret_cast<half4*>(h1out + ((size_t)r*512 + tbase + fdt)*128 + n) = v;
  }
}

// ---------------- layer 1: 1 row/block, K_in = 128 (4 ktiles), fused head ----------------
__global__ __launch_bounds__(256, 2) void lstm_l1(const _Float16* __restrict__ h1in,
    const _Float16* __restrict__ w1f, const float* __restrict__ bias1,
    const float* __restrict__ wlin, const float* __restrict__ blin,
    float* __restrict__ out)
{
  const int tid = threadIdx.x;
  const int lane = tid & 63;
  const int w = tid >> 6;
  const int li = lane & 15;
  const int r = blockIdx.x;

  __shared__ float preLDS[2][8192];       // 64 KB
  __shared__ half8 aF[2][256];            // 4 ktiles, 8 KB
  __shared__ half8 hA[2][16];             // 512 B
  __shared__ float head[128];

  if (tid < 128) ((int*)hA)[tid] = 0;

  // resident recurrent weights: kt 4..7
  half8 bfr[4][4][2];
#pragma unroll
  for (int kt = 0; kt < 4; ++kt)
#pragma unroll
    for (int g = 0; g < 4; ++g)
#pragma unroll
      for (int ct = 0; ct < 2; ++ct) {
        int frag = (kt+4)*32 + g*8 + w + 4*ct;
        bfr[kt][g][ct] = *reinterpret_cast<const half8*>(w1f + (size_t)(frag*64 + lane)*8);
        asm volatile("" : "+a"(bfr[kt][g][ct]));
      }
  float b_v[4][2];
#pragma unroll
  for (int g = 0; g < 4; ++g) {
    b_v[g][0] = bias1[g*128 + w*16 + li];
    b_v[g][1] = bias1[g*128 + (w+4)*16 + li];
  }

  // staging: thread -> (step-in-batch, col-octet); fp16 passthrough (16B)
  const int sdt = tid >> 4, sc8 = (tid & 15) * 8;
  const int sidx = ((sc8>>5)*64 + sdt + (((sc8&31)>>3)<<4))*8;

  const bool arow = (li == 0);
  const int kgrp = lane >> 4;
  const int en0 = w*16 + li;
  const int en1 = en0 + 64;
  const int eoff0 = ((en0>>5)*4 + ((en0&31)>>3))*8 + (en0&7);
  const int eoff1 = ((en1>>5)*4 + ((en1&31)>>3))*8 + (en1&7);
  const float wl0 = (lane < 16) ? wlin[en0] : 0.f;
  const float wl1 = (lane < 16) ? wlin[en1] : 0.f;
  float cst0 = 0.f, cst1 = 0.f, hl0 = 0.f, hl1 = 0.f;

  // prologue: stage batches 0 and 1
  {
    uint4 v0 = *reinterpret_cast<const uint4*>(h1in + ((size_t)r*512 + sdt)*128 + sc8);
    uint4 v1 = *reinterpret_cast<const uint4*>(h1in + ((size_t)r*512 + 16 + sdt)*128 + sc8);
    *reinterpret_cast<uint4*>(((_Float16*)aF[0]) + sidx) = v0;
    *reinterpret_cast<uint4*>(((_Float16*)aF[1]) + sidx) = v1;
  }
  __syncthreads();
  {                                        // project batch 0 -> preLDS[0]
    const _Float16* wp = w1f; asm volatile("" : "+v"(wp));
    floatx4 accP[4][2];
#pragma unroll
    for (int g = 0; g < 4; ++g)
#pragma unroll
      for (int ct = 0; ct < 2; ++ct) { float bb = b_v[g][ct]; accP[g][ct] = (floatx4){bb,bb,bb,bb}; }
#pragma unroll
    for (int kt = 0; kt < 4; ++kt) {
      half8 af = aF[0][kt*64 + lane];
#pragma unroll
      for (int g = 0; g < 4; ++g)
#pragma unroll
        for (int ct = 0; ct < 2; ++ct) {
          half8 wfr = *reinterpret_cast<const half8*>(wp + (size_t)((kt*32 + g*8 + w + 4*ct)*64 + lane)*8);
          accP[g][ct] = __builtin_amdgcn_mfma_f32_16x16x32_f16(af, wfr, accP[g][ct], 0, 0, 0);
        }
    }
#pragma unroll
    for (int reg = 0; reg < 4; ++reg) {
      int m = (lane>>4)*4 + reg;
      floatx4 pv0 = (floatx4){accP[0][0][reg], accP[1][0][reg], accP[2][0][reg], accP[3][0][reg]};
      floatx4 pv1 = (floatx4){accP[0][1][reg], accP[1][1][reg], accP[2][1][reg], accP[3][1][reg]};
      *reinterpret_cast<floatx4*>(&preLDS[0][(m*128 + en0)*4]) = pv0;
      *reinterpret_cast<floatx4*>(&preLDS[0][(m*128 + en1)*4]) = pv1;
    }
  }

  half8 a0 = {}, a1 = {}, a2 = {}, a3 = {};
  uint4 sv;

  for (int t = 0; t < 512; ++t) {
    const int bb = t >> 4;
    __syncthreads();
    if ((t & 15) == 0) {
      if (bb < 30) {                       // issue stage load for batch bb+2
        sv = *reinterpret_cast<const uint4*>(h1in + ((size_t)r*512 + (bb+2)*16 + sdt)*128 + sc8);
      }
      if (bb < 31) {                       // project batch bb+1 -> preLDS[(bb+1)&1]
        int slot = (bb+1) & 1;
        const _Float16* wp = w1f; asm volatile("" : "+v"(wp));
        floatx4 accP[4][2];
#pragma unroll
        for (int g = 0; g < 4; ++g)
#pragma unroll
          for (int ct = 0; ct < 2; ++ct) { float bv = b_v[g][ct]; accP[g][ct] = (floatx4){bv,bv,bv,bv}; }
#pragma unroll
        for (int kt = 0; kt < 4; ++kt) {
          half8 af = aF[slot][kt*64 + lane];
#pragma unroll
          for (int g = 0; g < 4; ++g)
#pragma unroll
            for (int ct = 0; ct < 2; ++ct) {
              half8 wfr = *reinterpret_cast<const half8*>(wp + (size_t)((kt*32 + g*8 + w + 4*ct)*64 + lane)*8);
              accP[g][ct] = __builtin_amdgcn_mfma_f32_16x16x32_f16(af, wfr, accP[g][ct], 0, 0, 0);
            }
        }
#pragma unroll
        for (int reg = 0; reg < 4; ++reg) {
          int m = (lane>>4)*4 + reg;
          floatx4 pv0 = (floatx4){accP[0][0][reg], accP[1][0][reg], accP[2][0][reg], accP[3][0][reg]};
          floatx4 pv1 = (floatx4){accP[0][1][reg], accP[1][1][reg], accP[2][1][reg], accP[3][1][reg]};
          *reinterpret_cast<floatx4*>(&preLDS[slot][(m*128 + en0)*4]) = pv0;
          *reinterpret_cast<floatx4*>(&preLDS[slot][(m*128 + en1)*4]) = pv1;
        }
      }
    }
    if ((t & 15) == 8 && bb < 30) {        // write stashed batch bb+2 -> aF[bb&1]
      *reinterpret_cast<uint4*>(((_Float16*)aF[bb&1]) + sidx) = sv;
    }

    floatx4 p40 = (floatx4){0.f,0.f,0.f,0.f}, p41 = (floatx4){0.f,0.f,0.f,0.f};
    if (lane < 16) {
      int m = t & 15;
      p40 = *reinterpret_cast<const floatx4*>(&preLDS[bb & 1][(m*128 + en0)*4]);
      p41 = *reinterpret_cast<const floatx4*>(&preLDS[bb & 1][(m*128 + en1)*4]);
    }
    floatx4 acc[4][2];
#pragma unroll
    for (int g = 0; g < 4; ++g) {
      acc[g][0] = (floatx4){0.f,0.f,0.f,0.f};
      acc[g][1] = (floatx4){0.f,0.f,0.f,0.f};
    }

    const int cur = t & 1;
    if (arow) {
      a0 = hA[cur][ 0 + kgrp];
      a1 = hA[cur][ 4 + kgrp];
      a2 = hA[cur][ 8 + kgrp];
      a3 = hA[cur][12 + kgrp];
    }
#pragma unroll
    for (int g = 0; g < 4; ++g) {
      acc[g][0] = __builtin_amdgcn_mfma_f32_16x16x32_f16(a0, bfr[0][g][0], acc[g][0], 0, 0, 0);
      acc[g][1] = __builtin_amdgcn_mfma_f32_16x16x32_f16(a0, bfr[0][g][1], acc[g][1], 0, 0, 0);
    }
#pragma unroll
    for (int g = 0; g < 4; ++g) {
      acc[g][0] = __builtin_amdgcn_mfma_f32_16x16x32_f16(a1, bfr[1][g][0], acc[g][0], 0, 0, 0);
      acc[g][1] = __builtin_amdgcn_mfma_f32_16x16x32_f16(a1, bfr[1][g][1], acc[g][1], 0, 0, 0);
    }
#pragma unroll
    for (int g = 0; g < 4; ++g) {
      acc[g][0] = __builtin_amdgcn_mfma_f32_16x16x32_f16(a2, bfr[2][g][0], acc[g][0], 0, 0, 0);
      acc[g][1] = __builtin_amdgcn_mfma_f32_16x16x32_f16(a2, bfr[2][g][1], acc[g][1], 0, 0, 0);
    }
#pragma unroll
    for (int g = 0; g < 4; ++g) {
      acc[g][0] = __builtin_amdgcn_mfma_f32_16x16x32_f16(a3, bfr[3][g][0], acc[g][0], 0, 0, 0);
      acc[g][1] = __builtin_amdgcn_mfma_f32_16x16x32_f16(a3, bfr[3][g][1], acc[g][1], 0, 0, 0);
    }

    if (lane < 16) {
      float i0 = fast_sigmoid(p40[0] + acc[0][0][0]);
      float f0 = fast_sigmoid(p40[1] + acc[1][0][0]);
      float g0 = fast_tanh  (p40[2] + acc[2][0][0]);
      float o0 = fast_sigmoid(p40[3] + acc[3][0][0]);
      float i1 = fast_sigmoid(p41[0] + acc[0][1][0]);
      float f1 = fast_sigmoid(p41[1] + acc[1][1][0]);
      float g1 = fast_tanh  (p41[2] + acc[2][1][0]);
      float o1 = fast_sigmoid(p41[3] + acc[3][1][0]);
      cst0 = f0*cst0 + i0*g0;
      cst1 = f1*cst1 + i1*g1;
      hl0 = o0*fast_tanh(cst0);
      hl1 = o1*fast_tanh(cst1);
      ((_Float16*)hA[cur^1])[eoff0] = (_Float16)hl0;
      ((_Float16*)hA[cur^1])[eoff1] = (_Float16)hl1;
    }
  }

  // fused head: out[r] = sum_n h_last[n]*wlin[n] + blin
  if (lane < 16) {
    head[en0] = hl0 * wl0;
    head[en1] = hl1 * wl1;
  }
  __syncthreads();
  if (tid < 64) {
    float s = head[tid] + head[tid + 64];
#pragma unroll
    for (int off = 32; off > 0; off >>= 1) s += __shfl_xor(s, off, 64);
    if (tid == 0) out[r] = s + blin[0];
  }
}

extern "C" void kernel_launch(void* const* d_in, const int* in_sizes, int n_in,
                              void* d_out, int out_size, void* d_ws, size_t ws_size,
                              hipStream_t stream)
{
  const float* x    = (const float*)d_in[0];
  const float* wih0 = (const float*)d_in[1];
  const float* whh0 = (const float*)d_in[2];
  const float* bih0 = (const float*)d_in[3];
  const float* bhh0 = (const float*)d_in[4];
  const float* wih1 = (const float*)d_in[5];
  const float* whh1 = (const float*)d_in[6];
  const float* bih1 = (const float*)d_in[7];
  const float* bhh1 = (const float*)d_in[8];
  const float* wlin = (const float*)d_in[9];
  const float* blin = (const float*)d_in[10];
  float* out = (float*)d_out;

  char* ws = (char*)d_ws;
  _Float16* w0f = (_Float16*)(ws);               // 196608 B
  _Float16* w1f = (_Float16*)(ws + 196608);      // 262144 B
  float* bias0  = (float*)(ws + 458752);         // 2048 B
  float* bias1  = (float*)(ws + 460800);         // 2048 B
  _Float16* h1  = (_Float16*)(ws + 1048576);     // 64 MB inter-layer buffer

  prep_kernel<<<256, 256, 0, stream>>>(wih0, whh0, bih0, bhh0, wih1, whh1, bih1, bhh1,
                                       w0f, w1f, bias0, bias1);
  lstm_l0<<<512, 256, 0, stream>>>(x, w0f, bias0, h1);
  lstm_l1<<<512, 256, 0, stream>>>(h1, w1f, bias1, wlin, blin, out);
}

// Round 5
// 878.650 us; speedup vs baseline: 2.2091x; 2.2091x over previous
//
#include <hip/hip_runtime.h>

typedef _Float16 half8 __attribute__((ext_vector_type(8)));
typedef _Float16 half4 __attribute__((ext_vector_type(4)));
typedef _Float16 half2v __attribute__((ext_vector_type(2)));
typedef float floatx4 __attribute__((ext_vector_type(4)));

__device__ __forceinline__ float fast_rcp(float x) { return __builtin_amdgcn_rcpf(x); }
__device__ __forceinline__ float fast_sigmoid(float x) {
  return fast_rcp(1.f + __expf(-x));
}
__device__ __forceinline__ float fast_tanh(float x) {
  return 1.f - 2.f * fast_rcp(1.f + __expf(2.f * x));
}

// ---------------- prep: fp16 fragment-ordered weights + bias sums ----------------
// B-frag layout for mfma_f32_16x16x32_f16: lane L, reg j holds
// W[n = ntile*16 + (L&15)][k = ktile*32 + (L>>4)*8 + j].
// Buffer: [ktile][ntile(32)][lane(64)][8 f16]. Verified correct across all rounds.
__global__ void prep_kernel(const float* __restrict__ wih0, const float* __restrict__ whh0,
                            const float* __restrict__ bih0, const float* __restrict__ bhh0,
                            const float* __restrict__ wih1, const float* __restrict__ whh1,
                            const float* __restrict__ bih1, const float* __restrict__ bhh1,
                            _Float16* __restrict__ w0f, _Float16* __restrict__ w1f,
                            float* __restrict__ bias0, float* __restrict__ bias1)
{
  int stride = gridDim.x * blockDim.x;
  int idx0 = blockIdx.x * blockDim.x + threadIdx.x;
  const int N0 = 6*32*64*8;      // layer0: K=192 (x 64 | h 128)
  const int N1 = 8*32*64*8;      // layer1: K=256 (h1 128 | h 128)
  for (int e = idx0; e < N0 + N1 + 1024; e += stride) {
    if (e < N0) {
      int j = e & 7; int le = e >> 3; int lane = le & 63; int frag = le >> 6;
      int kt = frag >> 5, ntile = frag & 31;
      int n = ntile*16 + (lane & 15);
      int kk = kt*32 + ((lane >> 4) << 3) + j;
      float v = (kk < 64) ? wih0[n*64 + kk] : whh0[n*128 + (kk - 64)];
      w0f[e] = (_Float16)v;
    } else if (e < N0 + N1) {
      int e2 = e - N0;
      int j = e2 & 7; int le = e2 >> 3; int lane = le & 63; int frag = le >> 6;
      int kt = frag >> 5, ntile = frag & 31;
      int n = ntile*16 + (lane & 15);
      int kk = kt*32 + ((lane >> 4) << 3) + j;
      float v = (kk < 128) ? wih1[n*128 + kk] : whh1[n*128 + (kk - 128)];
      w1f[e2] = (_Float16)v;
    } else {
      int i = e - (N0 + N1);
      if (i < 512) bias0[i] = bih0[i] + bhh0[i];
      else         bias1[i - 512] = bih1[i - 512] + bhh1[i - 512];
    }
  }
}

// ---------------- layer 0 ----------------
// Round-3 structure (all weights AGPR-resident, 8 waves, 2 rows/block) plus:
//  (a) persistent acc: only element 0 reseeded per step with the PREFETCHED
//      pre-activation (p4 loaded one phase early; preLDS columns are
//      wave-private so only lgkm ordering is needed). Removes 16 zero-movs
//      + 4 adds/step and takes the preLDS wait fully off the critical path.
//      Garbage C-rows are inert: their A-rows are always zero.
//  (b) projection split into 2 chunks at window phases 2,3 (stores at chunk
//      end); hist flush moved to phase 5. Uniform phases, no boundary bulge.
__global__ __launch_bounds__(512, 2) void lstm_l0(const float* __restrict__ x,
    const _Float16* __restrict__ w0f, const float* __restrict__ bias0,
    _Float16* __restrict__ h1out)
{
  const int tid = threadIdx.x;
  const int lane = tid & 63;
  const int w = tid >> 6;
  const int r0 = blockIdx.x * 2;

  __shared__ float preLDS[2][8192];       // 2 x 32 KB pre-activation buffers
  __shared__ half8 aF[2][2*64];           // input A-frags, 2 ktiles (K=64)
  __shared__ half8 hA[2][4*8];            // compact recurrent frags (1 KB)
  __shared__ _Float16 hist[16][2][128];   // h history ring (8 KB)

  for (int i = tid; i < 2*4*8*4; i += 512) ((int*)hA)[i] = 0;

  half8 bf[6][4];                         // 24 frags = 96 AGPRs
#pragma unroll
  for (int kt = 0; kt < 6; ++kt)
#pragma unroll
    for (int g = 0; g < 4; ++g) {
      int frag = kt*32 + (g*8 + w);
      bf[kt][g] = *reinterpret_cast<const half8*>(w0f + (size_t)(frag*64 + lane)*8);
      asm volatile("" : "+a"(bf[kt][g]));
    }
  float bias_v[4];
#pragma unroll
  for (int g = 0; g < 4; ++g) bias_v[g] = bias0[g*128 + w*16 + (lane & 15)];

  // staging: thread -> (dt, r, col-pair); full A-frag half index
  const int sdt = tid >> 6, sr = (tid >> 5) & 1, scp = (tid & 31) * 2;
  const int sm = sdt*2 + sr;
  const int sidx = ((scp>>5)*64 + sm + (((scp&31)>>3)<<4))*8 + (scp & 7);

  const bool arow = (lane & 11) == 0;
  const int cIdx = ((lane >> 4) << 1) | ((lane >> 2) & 1);
  const int rb = lane >> 4;
  const int en = w*16 + (lane & 15);
  const int eoff = ((en>>5)*8 + ((en&31)>>3)*2 + rb)*8 + (en&7);
  float cst = 0.f;

  // prologue: stage batches 0 and 1
  {
    float2 v0 = *reinterpret_cast<const float2*>(x + ((size_t)(r0+sr)*512 + sdt)*64 + scp);
    float2 v1 = *reinterpret_cast<const float2*>(x + ((size_t)(r0+sr)*512 + 8 + sdt)*64 + scp);
    half2v h0; h0[0] = (_Float16)v0.x; h0[1] = (_Float16)v0.y;
    half2v h1v; h1v[0] = (_Float16)v1.x; h1v[1] = (_Float16)v1.y;
    *reinterpret_cast<half2v*>(((_Float16*)aF[0]) + sidx) = h0;
    *reinterpret_cast<half2v*>(((_Float16*)aF[1]) + sidx) = h1v;
  }
  __syncthreads();
  {                                        // pre[batch0] -> preLDS[0]
    floatx4 accP0[4];
#pragma unroll
    for (int g = 0; g < 4; ++g) { float bb = bias_v[g]; accP0[g] = (floatx4){bb,bb,bb,bb}; }
#pragma unroll
    for (int kt = 0; kt < 2; ++kt) {
      half8 af = aF[0][kt*64 + lane];
#pragma unroll
      for (int g = 0; g < 4; ++g)
        accP0[g] = __builtin_amdgcn_mfma_f32_16x16x32_f16(af, bf[kt][g], accP0[g], 0, 0, 0);
    }
#pragma unroll
    for (int reg = 0; reg < 4; ++reg) {
      int m = ((lane>>4)<<2) + reg;
      floatx4 pv = (floatx4){accP0[0][reg], accP0[1][reg], accP0[2][reg], accP0[3][reg]};
      *reinterpret_cast<floatx4*>(&preLDS[0][(m*128 + en)*4]) = pv;
    }
  }

  half8 a2 = {}, a3 = {}, a4 = {}, a5 = {};
  float2 sv;                               // stage stash (T14 split)
  floatx4 accP[4];                         // smeared projection accumulator
  floatx4 acc[4];                          // persistent step accumulator
#pragma unroll
  for (int g = 0; g < 4; ++g) { acc[g] = (floatx4){0.f,0.f,0.f,0.f}; accP[g] = acc[g]; }

  // prefetch p4 for t=0 (same-wave preLDS columns: lgkm ordering only)
  floatx4 p4c = (floatx4){0.f,0.f,0.f,0.f};
  if (lane < 32)
    p4c = *reinterpret_cast<const floatx4*>(&preLDS[0][(rb*128 + en)*4]);

  for (int t = 0; t < 512; ++t) {
    const int b = t >> 3;
    __syncthreads();
    const int ph = t & 7;
    if (ph == 0 && b < 62) {               // issue stage load for batch b+2
      int s = (b+2)*8 + sdt;
      sv = *reinterpret_cast<const float2*>(x + ((size_t)(r0+sr)*512 + s)*64 + scp);
    }
    if (ph == 1 && b < 62) {               // write stashed batch b+2 -> aF[b&1]
      half2v hv; hv[0] = (_Float16)sv.x; hv[1] = (_Float16)sv.y;
      *reinterpret_cast<half2v*>(((_Float16*)aF[b&1]) + sidx) = hv;
    }
    if (ph == 2 && b < 63) {               // proj chunk A (kt0) for batch b+1
      int slot = (b+1) & 1;
#pragma unroll
      for (int g = 0; g < 4; ++g) { float bb = bias_v[g]; accP[g] = (floatx4){bb,bb,bb,bb}; }
      half8 af = aF[slot][lane];
#pragma unroll
      for (int g = 0; g < 4; ++g)
        accP[g] = __builtin_amdgcn_mfma_f32_16x16x32_f16(af, bf[0][g], accP[g], 0, 0, 0);
    }
    if (ph == 3 && b < 63) {               // proj chunk B (kt1) + stores
      int slot = (b+1) & 1;
      half8 af = aF[slot][64 + lane];
#pragma unroll
      for (int g = 0; g < 4; ++g)
        accP[g] = __builtin_amdgcn_mfma_f32_16x16x32_f16(af, bf[1][g], accP[g], 0, 0, 0);
#pragma unroll
      for (int reg = 0; reg < 4; ++reg) {
        int m = ((lane>>4)<<2) + reg;
        floatx4 pv = (floatx4){accP[0][reg], accP[1][reg], accP[2][reg], accP[3][reg]};
        *reinterpret_cast<floatx4*>(&preLDS[slot][(m*128 + en)*4]) = pv;
      }
    }
    if (ph == 5 && t >= 13) {              // coalesced flush of steps t-13..t-6
      int tbase = t - 13;
      int fr = tid >> 8, rest = tid & 255;
      int fdt = rest >> 5, n = (rest & 31) * 4;
      half4 v = *reinterpret_cast<const half4*>(&hist[(tbase + fdt) & 15][fr][n]);
      *reinterpret_cast<half4*>(h1out + ((size_t)(r0 + fr)*512 + tbase + fdt)*128 + n) = v;
    }

    // seed: element 0 only (rows {0,4}); other C rows provably stay 0
    acc[0][0] = p4c[0]; acc[1][0] = p4c[1]; acc[2][0] = p4c[2]; acc[3][0] = p4c[3];

    const int cur = t & 1;
    if (arow) {
      a2 = hA[cur][0*8 + cIdx];
      a3 = hA[cur][1*8 + cIdx];
      a4 = hA[cur][2*8 + cIdx];
      a5 = hA[cur][3*8 + cIdx];
    }
#pragma unroll
    for (int g = 0; g < 4; ++g)
      acc[g] = __builtin_amdgcn_mfma_f32_16x16x32_f16(a2, bf[2][g], acc[g], 0, 0, 0);
#pragma unroll
    for (int g = 0; g < 4; ++g)
      acc[g] = __builtin_amdgcn_mfma_f32_16x16x32_f16(a3, bf[3][g], acc[g], 0, 0, 0);
#pragma unroll
    for (int g = 0; g < 4; ++g)
      acc[g] = __builtin_amdgcn_mfma_f32_16x16x32_f16(a4, bf[4][g], acc[g], 0, 0, 0);
#pragma unroll
    for (int g = 0; g < 4; ++g)
      acc[g] = __builtin_amdgcn_mfma_f32_16x16x32_f16(a5, bf[5][g], acc[g], 0, 0, 0);

    // prefetch p4 for t+1 (wave-private preLDS; full phase of slack)
    if (lane < 32 && t < 511) {
      int tn = t + 1;
      int mstep = ((tn & 7) << 1) + rb;
      p4c = *reinterpret_cast<const floatx4*>(&preLDS[(tn >> 3) & 1][(mstep*128 + en)*4]);
    }

    if (lane < 32) {
      float ii = fast_sigmoid(acc[0][0]);
      float ff = fast_sigmoid(acc[1][0]);
      float gg = fast_tanh(acc[2][0]);
      float oo = fast_sigmoid(acc[3][0]);
      cst = ff*cst + ii*gg;
      float hv2 = oo*fast_tanh(cst);
      _Float16 hh = (_Float16)hv2;
      ((_Float16*)hA[cur^1])[eoff] = hh;
      hist[t & 15][rb][en] = hh;
    }
  }
  __syncthreads();
  {                                        // final flush: steps 504..511
    int tbase = 504;
    int fr = tid >> 8, rest = tid & 255;
    int fdt = rest >> 5, n = (rest & 31) * 4;
    half4 v = *reinterpret_cast<const half4*>(&hist[(tbase + fdt) & 15][fr][n]);
    *reinterpret_cast<half4*>(h1out + ((size_t)(r0 + fr)*512 + tbase + fdt)*128 + n) = v;
  }
}

// ---------------- layer 1: K_in = 128 (4 ktiles), fused linear head ----------------
// Same edits as layer 0 (persistent acc + p4 prefetch; proj chunks at ph2/ph3).
__global__ __launch_bounds__(512, 2) void lstm_l1(const _Float16* __restrict__ h1in,
    const _Float16* __restrict__ w1f, const float* __restrict__ bias1,
    const float* __restrict__ wlin, const float* __restrict__ blin,
    float* __restrict__ out)
{
  const int tid = threadIdx.x;
  const int lane = tid & 63;
  const int w = tid >> 6;
  const int r0 = blockIdx.x * 2;

  __shared__ float preLDS[2][8192];       // 2 x 32 KB
  __shared__ half8 aF[2][4*64];           // input A-frags, 4 ktiles (K=128)
  __shared__ half8 hA[2][4*8];
  __shared__ float head[256];

  for (int i = tid; i < 2*4*8*4; i += 512) ((int*)hA)[i] = 0;

  half8 bf[8][4];                         // 32 frags = 128 AGPRs
#pragma unroll
  for (int kt = 0; kt < 8; ++kt)
#pragma unroll
    for (int g = 0; g < 4; ++g) {
      int frag = kt*32 + (g*8 + w);
      bf[kt][g] = *reinterpret_cast<const half8*>(w1f + (size_t)(frag*64 + lane)*8);
      asm volatile("" : "+a"(bf[kt][g]));
    }
  float bias_v[4];
#pragma unroll
  for (int g = 0; g < 4; ++g) bias_v[g] = bias1[g*128 + w*16 + (lane & 15)];

  // staging: thread -> (dt, r, col-quad); fp16 passthrough (8B)
  const int sdt = tid >> 6, sr = (tid >> 5) & 1, scq = (tid & 31) * 4;
  const int sm = sdt*2 + sr;
  const int sidx = ((scq>>5)*64 + sm + (((scq&31)>>3)<<4))*8 + (scq & 7);

  const bool arow = (lane & 11) == 0;
  const int cIdx = ((lane >> 4) << 1) | ((lane >> 2) & 1);
  const int rb = lane >> 4;
  const int en = w*16 + (lane & 15);
  const int eoff = ((en>>5)*8 + ((en&31)>>3)*2 + rb)*8 + (en&7);
  const float wl = (lane < 32) ? wlin[en] : 0.f;
  float cst = 0.f;
  float hl = 0.f;

  // prologue: stage batches 0 and 1
  {
    uint2 v0 = *reinterpret_cast<const uint2*>(h1in + ((size_t)(r0+sr)*512 + sdt)*128 + scq);
    uint2 v1 = *reinterpret_cast<const uint2*>(h1in + ((size_t)(r0+sr)*512 + 8 + sdt)*128 + scq);
    *reinterpret_cast<uint2*>(((_Float16*)aF[0]) + sidx) = v0;
    *reinterpret_cast<uint2*>(((_Float16*)aF[1]) + sidx) = v1;
  }
  __syncthreads();
  {                                        // pre[batch0] -> preLDS[0]
    floatx4 accP0[4];
#pragma unroll
    for (int g = 0; g < 4; ++g) { float bb = bias_v[g]; accP0[g] = (floatx4){bb,bb,bb,bb}; }
#pragma unroll
    for (int kt = 0; kt < 4; ++kt) {
      half8 af = aF[0][kt*64 + lane];
#pragma unroll
      for (int g = 0; g < 4; ++g)
        accP0[g] = __builtin_amdgcn_mfma_f32_16x16x32_f16(af, bf[kt][g], accP0[g], 0, 0, 0);
    }
#pragma unroll
    for (int reg = 0; reg < 4; ++reg) {
      int m = ((lane>>4)<<2) + reg;
      floatx4 pv = (floatx4){accP0[0][reg], accP0[1][reg], accP0[2][reg], accP0[3][reg]};
      *reinterpret_cast<floatx4*>(&preLDS[0][(m*128 + en)*4]) = pv;
    }
  }

  half8 a4 = {}, a5 = {}, a6 = {}, a7 = {};
  uint2 sv;                                // stage stash (T14 split)
  floatx4 accP[4];
  floatx4 acc[4];
#pragma unroll
  for (int g = 0; g < 4; ++g) { acc[g] = (floatx4){0.f,0.f,0.f,0.f}; accP[g] = acc[g]; }

  floatx4 p4c = (floatx4){0.f,0.f,0.f,0.f};
  if (lane < 32)
    p4c = *reinterpret_cast<const floatx4*>(&preLDS[0][(rb*128 + en)*4]);

  for (int t = 0; t < 512; ++t) {
    const int b = t >> 3;
    __syncthreads();
    const int ph = t & 7;
    if (ph == 0 && b < 62) {               // issue stage load for batch b+2
      int s = (b+2)*8 + sdt;
      sv = *reinterpret_cast<const uint2*>(h1in + ((size_t)(r0+sr)*512 + s)*128 + scq);
    }
    if (ph == 1 && b < 62) {               // write stashed batch b+2 -> aF[b&1]
      *reinterpret_cast<uint2*>(((_Float16*)aF[b&1]) + sidx) = sv;
    }
    if (ph == 2 && b < 63) {               // proj chunk A (kt0,kt1) for batch b+1
      int slot = (b+1) & 1;
#pragma unroll
      for (int g = 0; g < 4; ++g) { float bb = bias_v[g]; accP[g] = (floatx4){bb,bb,bb,bb}; }
#pragma unroll
      for (int kt = 0; kt < 2; ++kt) {
        half8 af = aF[slot][kt*64 + lane];
#pragma unroll
        for (int g = 0; g < 4; ++g)
          accP[g] = __builtin_amdgcn_mfma_f32_16x16x32_f16(af, bf[kt][g], accP[g], 0, 0, 0);
      }
    }
    if (ph == 3 && b < 63) {               // proj chunk B (kt2,kt3) + stores
      int slot = (b+1) & 1;
#pragma unroll
      for (int kt = 2; kt < 4; ++kt) {
        half8 af = aF[slot][kt*64 + lane];
#pragma unroll
        for (int g = 0; g < 4; ++g)
          accP[g] = __builtin_amdgcn_mfma_f32_16x16x32_f16(af, bf[kt][g], accP[g], 0, 0, 0);
      }
#pragma unroll
      for (int reg = 0; reg < 4; ++reg) {
        int m = ((lane>>4)<<2) + reg;
        floatx4 pv = (floatx4){accP[0][reg], accP[1][reg], accP[2][reg], accP[3][reg]};
        *reinterpret_cast<floatx4*>(&preLDS[slot][(m*128 + en)*4]) = pv;
      }
    }

    // seed: element 0 only
    acc[0][0] = p4c[0]; acc[1][0] = p4c[1]; acc[2][0] = p4c[2]; acc[3][0] = p4c[3];

    const int cur = t & 1;
    if (arow) {
      a4 = hA[cur][0*8 + cIdx];
      a5 = hA[cur][1*8 + cIdx];
      a6 = hA[cur][2*8 + cIdx];
      a7 = hA[cur][3*8 + cIdx];
    }
#pragma unroll
    for (int g = 0; g < 4; ++g)
      acc[g] = __builtin_amdgcn_mfma_f32_16x16x32_f16(a4, bf[4][g], acc[g], 0, 0, 0);
#pragma unroll
    for (int g = 0; g < 4; ++g)
      acc[g] = __builtin_amdgcn_mfma_f32_16x16x32_f16(a5, bf[5][g], acc[g], 0, 0, 0);
#pragma unroll
    for (int g = 0; g < 4; ++g)
      acc[g] = __builtin_amdgcn_mfma_f32_16x16x32_f16(a6, bf[6][g], acc[g], 0, 0, 0);
#pragma unroll
    for (int g = 0; g < 4; ++g)
      acc[g] = __builtin_amdgcn_mfma_f32_16x16x32_f16(a7, bf[7][g], acc[g], 0, 0, 0);

    // prefetch p4 for t+1
    if (lane < 32 && t < 511) {
      int tn = t + 1;
      int mstep = ((tn & 7) << 1) + rb;
      p4c = *reinterpret_cast<const floatx4*>(&preLDS[(tn >> 3) & 1][(mstep*128 + en)*4]);
    }

    if (lane < 32) {
      float ii = fast_sigmoid(acc[0][0]);
      float ff = fast_sigmoid(acc[1][0]);
      float gg = fast_tanh(acc[2][0]);
      float oo = fast_sigmoid(acc[3][0]);
      cst = ff*cst + ii*gg;
      hl = oo*fast_tanh(cst);
      ((_Float16*)hA[cur^1])[eoff] = (_Float16)hl;
    }
  }

  // fused head: out[r] = sum_n h_last[r][n]*wlin[n] + blin
  if (lane < 32) head[rb*128 + en] = hl * wl;
  __syncthreads();
  if (tid < 2) {
    float s = blin[0];
    for (int n = 0; n < 128; ++n) s += head[tid*128 + n];
    out[r0 + tid] = s;
  }
}

extern "C" void kernel_launch(void* const* d_in, const int* in_sizes, int n_in,
                              void* d_out, int out_size, void* d_ws, size_t ws_size,
                              hipStream_t stream)
{
  const float* x    = (const float*)d_in[0];
  const float* wih0 = (const float*)d_in[1];
  const float* whh0 = (const float*)d_in[2];
  const float* bih0 = (const float*)d_in[3];
  const float* bhh0 = (const float*)d_in[4];
  const float* wih1 = (const float*)d_in[5];
  const float* whh1 = (const float*)d_in[6];
  const float* bih1 = (const float*)d_in[7];
  const float* bhh1 = (const float*)d_in[8];
  const float* wlin = (const float*)d_in[9];
  const float* blin = (const float*)d_in[10];
  float* out = (float*)d_out;

  char* ws = (char*)d_ws;
  _Float16* w0f = (_Float16*)(ws);               // 196608 B
  _Float16* w1f = (_Float16*)(ws + 196608);      // 262144 B
  float* bias0  = (float*)(ws + 458752);         // 2048 B
  float* bias1  = (float*)(ws + 460800);         // 2048 B
  _Float16* h1  = (_Float16*)(ws + 1048576);     // 64 MB inter-layer buffer

  prep_kernel<<<256, 256, 0, stream>>>(wih0, whh0, bih0, bhh0, wih1, whh1, bih1, bhh1,
                                       w0f, w1f, bias0, bias1);
  lstm_l0<<<256, 512, 0, stream>>>(x, w0f, bias0, h1);
  lstm_l1<<<256, 512, 0, stream>>>(h1, w1f, bias1, wlin, blin, out);
}

// Round 6
// 673.947 us; speedup vs baseline: 2.8801x; 1.3037x over previous
//
#include <hip/hip_runtime.h>

typedef _Float16 half8 __attribute__((ext_vector_type(8)));
typedef _Float16 half4 __attribute__((ext_vector_type(4)));
typedef _Float16 half2v __attribute__((ext_vector_type(2)));
typedef float floatx4 __attribute__((ext_vector_type(4)));

template<int N> struct ic { static constexpr int value = N; };

__device__ __forceinline__ float fast_rcp(float x) { return __builtin_amdgcn_rcpf(x); }
__device__ __forceinline__ float fast_sigmoid(float x) {
  return fast_rcp(1.f + __expf(-x));
}
__device__ __forceinline__ float fast_tanh(float x) {
  return 1.f - 2.f * fast_rcp(1.f + __expf(2.f * x));
}

// ---------------- prep: fp16 fragment-ordered weights + bias sums ----------------
// B-frag layout for mfma_f32_16x16x32_f16: lane L, reg j holds
// W[n = ntile*16 + (L&15)][k = ktile*32 + (L>>4)*8 + j].
// Buffer: [ktile][ntile(32)][lane(64)][8 f16]. Verified correct across all rounds.
__global__ void prep_kernel(const float* __restrict__ wih0, const float* __restrict__ whh0,
                            const float* __restrict__ bih0, const float* __restrict__ bhh0,
                            const float* __restrict__ wih1, const float* __restrict__ whh1,
                            const float* __restrict__ bih1, const float* __restrict__ bhh1,
                            _Float16* __restrict__ w0f, _Float16* __restrict__ w1f,
                            float* __restrict__ bias0, float* __restrict__ bias1)
{
  int stride = gridDim.x * blockDim.x;
  int idx0 = blockIdx.x * blockDim.x + threadIdx.x;
  const int N0 = 6*32*64*8;      // layer0: K=192 (x 64 | h 128)
  const int N1 = 8*32*64*8;      // layer1: K=256 (h1 128 | h 128)
  for (int e = idx0; e < N0 + N1 + 1024; e += stride) {
    if (e < N0) {
      int j = e & 7; int le = e >> 3; int lane = le & 63; int frag = le >> 6;
      int kt = frag >> 5, ntile = frag & 31;
      int n = ntile*16 + (lane & 15);
      int kk = kt*32 + ((lane >> 4) << 3) + j;
      float v = (kk < 64) ? wih0[n*64 + kk] : whh0[n*128 + (kk - 64)];
      w0f[e] = (_Float16)v;
    } else if (e < N0 + N1) {
      int e2 = e - N0;
      int j = e2 & 7; int le = e2 >> 3; int lane = le & 63; int frag = le >> 6;
      int kt = frag >> 5, ntile = frag & 31;
      int n = ntile*16 + (lane & 15);
      int kk = kt*32 + ((lane >> 4) << 3) + j;
      float v = (kk < 128) ? wih1[n*128 + kk] : whh1[n*128 + (kk - 128)];
      w1f[e2] = (_Float16)v;
    } else {
      int i = e - (N0 + N1);
      if (i < 512) bias0[i] = bih0[i] + bhh0[i];
      else         bias1[i - 512] = bih1[i - 512] + bhh1[i - 512];
    }
  }
}

// ---------------- layer 0 ----------------
// Round-3 structure (all weights AGPR-resident, 8 waves, 2 rows/block, one
// barrier per step, T14 stage split, batched input projection) with the
// per-step VALU stream minimized:
//  - 16-step window pair fully specialized via compile-time TM (ic<>): every
//    LDS offset (hA[cur], preLDS[slot], hist[t&15], mstep) is an immediate;
//    zero phase tests or loop-index math inside steps.
//  - persistent accumulator, element-0-only reseed (garbage C rows are inert:
//    their A rows hold finite h values, accumulate bounded, never read).
//  - p4 prefetched one step ahead inside the masked epilogue region.
__global__ __launch_bounds__(512, 2) void lstm_l0(const float* __restrict__ x,
    const _Float16* __restrict__ w0f, const float* __restrict__ bias0,
    _Float16* __restrict__ h1out)
{
  const int tid = threadIdx.x;
  const int lane = tid & 63;
  const int w = tid >> 6;
  const int r0 = blockIdx.x * 2;

  __shared__ float preLDS[2][8192];       // 2 x 32 KB pre-activation buffers
  __shared__ half8 aF[2][2*64];           // input A-frags, 2 ktiles (K=64)
  __shared__ half8 hA[2][4*8];            // compact recurrent frags (1 KB)
  __shared__ _Float16 hist[16][2][128];   // h history ring (8 KB)

  for (int i = tid; i < 2*4*8*4; i += 512) ((int*)hA)[i] = 0;

  half8 bf[6][4];                         // 24 frags = 96 AGPRs
#pragma unroll
  for (int kt = 0; kt < 6; ++kt)
#pragma unroll
    for (int g = 0; g < 4; ++g) {
      int frag = kt*32 + (g*8 + w);
      bf[kt][g] = *reinterpret_cast<const half8*>(w0f + (size_t)(frag*64 + lane)*8);
      asm volatile("" : "+a"(bf[kt][g]));
    }
  float bias_v[4];
#pragma unroll
  for (int g = 0; g < 4; ++g) bias_v[g] = bias0[g*128 + w*16 + (lane & 15)];

  // staging: thread -> (dt, r, col-pair); full A-frag half index
  const int sdt = tid >> 6, sr = (tid >> 5) & 1, scp = (tid & 31) * 2;
  const int sm = sdt*2 + sr;
  const int sidx = ((scp>>5)*64 + sm + (((scp&31)>>3)<<4))*8 + (scp & 7);

  const bool arow = (lane & 11) == 0;
  const int cIdx = ((lane >> 4) << 1) | ((lane >> 2) & 1);
  const int rb = lane >> 4;
  const int en = w*16 + (lane & 15);
  const int eoff = ((en>>5)*8 + ((en&31)>>3)*2 + rb)*8 + (en&7);
  // flush mapping (hoisted)
  const int fr = tid >> 8, rest = tid & 255;
  const int fdt = rest >> 5, fn = (rest & 31) * 4;
  float cst = 0.f;

  // prologue: stage batches 0 and 1
  {
    float2 v0 = *reinterpret_cast<const float2*>(x + ((size_t)(r0+sr)*512 + sdt)*64 + scp);
    float2 v1 = *reinterpret_cast<const float2*>(x + ((size_t)(r0+sr)*512 + 8 + sdt)*64 + scp);
    half2v h0; h0[0] = (_Float16)v0.x; h0[1] = (_Float16)v0.y;
    half2v h1v; h1v[0] = (_Float16)v1.x; h1v[1] = (_Float16)v1.y;
    *reinterpret_cast<half2v*>(((_Float16*)aF[0]) + sidx) = h0;
    *reinterpret_cast<half2v*>(((_Float16*)aF[1]) + sidx) = h1v;
  }
  __syncthreads();
  {                                        // pre[batch0] -> preLDS[0]
    floatx4 accP[4];
#pragma unroll
    for (int g = 0; g < 4; ++g) { float bb = bias_v[g]; accP[g] = (floatx4){bb,bb,bb,bb}; }
#pragma unroll
    for (int kt = 0; kt < 2; ++kt) {
      half8 af = aF[0][kt*64 + lane];
#pragma unroll
      for (int g = 0; g < 4; ++g)
        accP[g] = __builtin_amdgcn_mfma_f32_16x16x32_f16(af, bf[kt][g], accP[g], 0, 0, 0);
    }
#pragma unroll
    for (int reg = 0; reg < 4; ++reg) {
      int m = ((lane>>4)<<2) + reg;
      floatx4 pv = (floatx4){accP[0][reg], accP[1][reg], accP[2][reg], accP[3][reg]};
      *reinterpret_cast<floatx4*>(&preLDS[0][(m*128 + en)*4]) = pv;
    }
  }

  half8 a2 = {}, a3 = {}, a4 = {}, a5 = {};
  float2 sv;
  floatx4 acc[4];
#pragma unroll
  for (int g = 0; g < 4; ++g) acc[g] = (floatx4){0.f,0.f,0.f,0.f};

  floatx4 p4c = (floatx4){0.f,0.f,0.f,0.f};
  if (lane < 32)
    p4c = *reinterpret_cast<const floatx4*>(&preLDS[0][(rb*128 + en)*4]);

  auto core = [&](auto tag) {
    constexpr int TM = decltype(tag)::value;   // t & 15
    constexpr int CUR = TM & 1;
    constexpr int TN = (TM + 1) & 15;
    if (arow) {
      a2 = hA[CUR][ 0 + cIdx];
      a3 = hA[CUR][ 8 + cIdx];
      a4 = hA[CUR][16 + cIdx];
      a5 = hA[CUR][24 + cIdx];
    }
    acc[0][0] = p4c[0]; acc[1][0] = p4c[1]; acc[2][0] = p4c[2]; acc[3][0] = p4c[3];
#pragma unroll
    for (int g = 0; g < 4; ++g)
      acc[g] = __builtin_amdgcn_mfma_f32_16x16x32_f16(a2, bf[2][g], acc[g], 0, 0, 0);
#pragma unroll
    for (int g = 0; g < 4; ++g)
      acc[g] = __builtin_amdgcn_mfma_f32_16x16x32_f16(a3, bf[3][g], acc[g], 0, 0, 0);
#pragma unroll
    for (int g = 0; g < 4; ++g)
      acc[g] = __builtin_amdgcn_mfma_f32_16x16x32_f16(a4, bf[4][g], acc[g], 0, 0, 0);
#pragma unroll
    for (int g = 0; g < 4; ++g)
      acc[g] = __builtin_amdgcn_mfma_f32_16x16x32_f16(a5, bf[5][g], acc[g], 0, 0, 0);
    if (lane < 32) {
      // prefetch next step's pre-activation (constant offsets; latency hidden
      // under the transcendental chain + next barrier's lgkm drain)
      p4c = *reinterpret_cast<const floatx4*>(
          &preLDS[TN >> 3][((((TN & 7) << 1) + rb)*128 + en)*4]);
      float ii = fast_sigmoid(acc[0][0]);
      float ff = fast_sigmoid(acc[1][0]);
      float gg = fast_tanh(acc[2][0]);
      float oo = fast_sigmoid(acc[3][0]);
      cst = ff*cst + ii*gg;
      float hv2 = oo*fast_tanh(cst);
      _Float16 hh = (_Float16)hv2;
      ((_Float16*)hA[CUR^1])[eoff] = hh;
      hist[TM][rb][en] = hh;
    }
  };

  auto window = [&](int B, auto slot_tag) {
    constexpr int SLOT = decltype(slot_tag)::value;
    __syncthreads();
    if (B < 62)                            // T14: issue stage load (batch B+2)
      sv = *reinterpret_cast<const float2*>(x + ((size_t)(r0+sr)*512 + (B+2)*8 + sdt)*64 + scp);
    if (B >= 1) {                          // coalesced flush of prev window
      int tbase = (B-1)*8;
      half4 v = *reinterpret_cast<const half4*>(&hist[((SLOT^1)<<3) + fdt][fr][fn]);
      *reinterpret_cast<half4*>(h1out + ((size_t)(r0+fr)*512 + tbase + fdt)*128 + fn) = v;
    }
    if (B < 63) {                          // project batch B+1 -> preLDS[SLOT^1]
      floatx4 accP[4];
#pragma unroll
      for (int g = 0; g < 4; ++g) { float bb = bias_v[g]; accP[g] = (floatx4){bb,bb,bb,bb}; }
#pragma unroll
      for (int kt = 0; kt < 2; ++kt) {
        half8 af = aF[SLOT^1][kt*64 + lane];
#pragma unroll
        for (int g = 0; g < 4; ++g)
          accP[g] = __builtin_amdgcn_mfma_f32_16x16x32_f16(af, bf[kt][g], accP[g], 0, 0, 0);
      }
#pragma unroll
      for (int reg = 0; reg < 4; ++reg) {
        int m = ((lane>>4)<<2) + reg;
        floatx4 pv = (floatx4){accP[0][reg], accP[1][reg], accP[2][reg], accP[3][reg]};
        *reinterpret_cast<floatx4*>(&preLDS[SLOT^1][(m*128 + en)*4]) = pv;
      }
    }
    core(ic<SLOT*8 + 0>{});
    __syncthreads();
    if (B < 62) {                          // T14: LDS-write of stashed batch
      half2v hv; hv[0] = (_Float16)sv.x; hv[1] = (_Float16)sv.y;
      *reinterpret_cast<half2v*>(((_Float16*)aF[SLOT]) + sidx) = hv;
    }
    core(ic<SLOT*8 + 1>{});
    __syncthreads(); core(ic<SLOT*8 + 2>{});
    __syncthreads(); core(ic<SLOT*8 + 3>{});
    __syncthreads(); core(ic<SLOT*8 + 4>{});
    __syncthreads(); core(ic<SLOT*8 + 5>{});
    __syncthreads(); core(ic<SLOT*8 + 6>{});
    __syncthreads(); core(ic<SLOT*8 + 7>{});
  };

  for (int bp = 0; bp < 32; ++bp) {
    window(2*bp,     ic<0>{});
    window(2*bp + 1, ic<1>{});
  }
  __syncthreads();
  {                                        // final flush: steps 504..511
    half4 v = *reinterpret_cast<const half4*>(&hist[8 + fdt][fr][fn]);
    *reinterpret_cast<half4*>(h1out + ((size_t)(r0+fr)*512 + 504 + fdt)*128 + fn) = v;
  }
}

// ---------------- layer 1: K_in = 128 (4 ktiles), fused linear head ----------------
// Same VALU-minimized structure as layer 0 (no hist ring, head at end).
__global__ __launch_bounds__(512, 2) void lstm_l1(const _Float16* __restrict__ h1in,
    const _Float16* __restrict__ w1f, const float* __restrict__ bias1,
    const float* __restrict__ wlin, const float* __restrict__ blin,
    float* __restrict__ out)
{
  const int tid = threadIdx.x;
  const int lane = tid & 63;
  const int w = tid >> 6;
  const int r0 = blockIdx.x * 2;

  __shared__ float preLDS[2][8192];       // 2 x 32 KB
  __shared__ half8 aF[2][4*64];           // input A-frags, 4 ktiles (K=128)
  __shared__ half8 hA[2][4*8];
  __shared__ float head[256];

  for (int i = tid; i < 2*4*8*4; i += 512) ((int*)hA)[i] = 0;

  half8 bf[8][4];                         // 32 frags = 128 AGPRs
#pragma unroll
  for (int kt = 0; kt < 8; ++kt)
#pragma unroll
    for (int g = 0; g < 4; ++g) {
      int frag = kt*32 + (g*8 + w);
      bf[kt][g] = *reinterpret_cast<const half8*>(w1f + (size_t)(frag*64 + lane)*8);
      asm volatile("" : "+a"(bf[kt][g]));
    }
  float bias_v[4];
#pragma unroll
  for (int g = 0; g < 4; ++g) bias_v[g] = bias1[g*128 + w*16 + (lane & 15)];

  // staging: thread -> (dt, r, col-quad); fp16 passthrough (8B)
  const int sdt = tid >> 6, sr = (tid >> 5) & 1, scq = (tid & 31) * 4;
  const int sm = sdt*2 + sr;
  const int sidx = ((scq>>5)*64 + sm + (((scq&31)>>3)<<4))*8 + (scq & 7);

  const bool arow = (lane & 11) == 0;
  const int cIdx = ((lane >> 4) << 1) | ((lane >> 2) & 1);
  const int rb = lane >> 4;
  const int en = w*16 + (lane & 15);
  const int eoff = ((en>>5)*8 + ((en&31)>>3)*2 + rb)*8 + (en&7);
  const float wl = (lane < 32) ? wlin[en] : 0.f;
  float cst = 0.f;
  float hl = 0.f;

  // prologue: stage batches 0 and 1
  {
    uint2 v0 = *reinterpret_cast<const uint2*>(h1in + ((size_t)(r0+sr)*512 + sdt)*128 + scq);
    uint2 v1 = *reinterpret_cast<const uint2*>(h1in + ((size_t)(r0+sr)*512 + 8 + sdt)*128 + scq);
    *reinterpret_cast<uint2*>(((_Float16*)aF[0]) + sidx) = v0;
    *reinterpret_cast<uint2*>(((_Float16*)aF[1]) + sidx) = v1;
  }
  __syncthreads();
  {                                        // pre[batch0] -> preLDS[0]
    floatx4 accP[4];
#pragma unroll
    for (int g = 0; g < 4; ++g) { float bb = bias_v[g]; accP[g] = (floatx4){bb,bb,bb,bb}; }
#pragma unroll
    for (int kt = 0; kt < 4; ++kt) {
      half8 af = aF[0][kt*64 + lane];
#pragma unroll
      for (int g = 0; g < 4; ++g)
        accP[g] = __builtin_amdgcn_mfma_f32_16x16x32_f16(af, bf[kt][g], accP[g], 0, 0, 0);
    }
#pragma unroll
    for (int reg = 0; reg < 4; ++reg) {
      int m = ((lane>>4)<<2) + reg;
      floatx4 pv = (floatx4){accP[0][reg], accP[1][reg], accP[2][reg], accP[3][reg]};
      *reinterpret_cast<floatx4*>(&preLDS[0][(m*128 + en)*4]) = pv;
    }
  }

  half8 a4 = {}, a5 = {}, a6 = {}, a7 = {};
  uint2 sv;
  floatx4 acc[4];
#pragma unroll
  for (int g = 0; g < 4; ++g) acc[g] = (floatx4){0.f,0.f,0.f,0.f};

  floatx4 p4c = (floatx4){0.f,0.f,0.f,0.f};
  if (lane < 32)
    p4c = *reinterpret_cast<const floatx4*>(&preLDS[0][(rb*128 + en)*4]);

  auto core = [&](auto tag) {
    constexpr int TM = decltype(tag)::value;   // t & 15
    constexpr int CUR = TM & 1;
    constexpr int TN = (TM + 1) & 15;
    if (arow) {
      a4 = hA[CUR][ 0 + cIdx];
      a5 = hA[CUR][ 8 + cIdx];
      a6 = hA[CUR][16 + cIdx];
      a7 = hA[CUR][24 + cIdx];
    }
    acc[0][0] = p4c[0]; acc[1][0] = p4c[1]; acc[2][0] = p4c[2]; acc[3][0] = p4c[3];
#pragma unroll
    for (int g = 0; g < 4; ++g)
      acc[g] = __builtin_amdgcn_mfma_f32_16x16x32_f16(a4, bf[4][g], acc[g], 0, 0, 0);
#pragma unroll
    for (int g = 0; g < 4; ++g)
      acc[g] = __builtin_amdgcn_mfma_f32_16x16x32_f16(a5, bf[5][g], acc[g], 0, 0, 0);
#pragma unroll
    for (int g = 0; g < 4; ++g)
      acc[g] = __builtin_amdgcn_mfma_f32_16x16x32_f16(a6, bf[6][g], acc[g], 0, 0, 0);
#pragma unroll
    for (int g = 0; g < 4; ++g)
      acc[g] = __builtin_amdgcn_mfma_f32_16x16x32_f16(a7, bf[7][g], acc[g], 0, 0, 0);
    if (lane < 32) {
      p4c = *reinterpret_cast<const floatx4*>(
          &preLDS[TN >> 3][((((TN & 7) << 1) + rb)*128 + en)*4]);
      float ii = fast_sigmoid(acc[0][0]);
      float ff = fast_sigmoid(acc[1][0]);
      float gg = fast_tanh(acc[2][0]);
      float oo = fast_sigmoid(acc[3][0]);
      cst = ff*cst + ii*gg;
      hl = oo*fast_tanh(cst);
      ((_Float16*)hA[CUR^1])[eoff] = (_Float16)hl;
    }
  };

  auto window = [&](int B, auto slot_tag) {
    constexpr int SLOT = decltype(slot_tag)::value;
    __syncthreads();
    if (B < 62)                            // T14: issue stage load (batch B+2)
      sv = *reinterpret_cast<const uint2*>(h1in + ((size_t)(r0+sr)*512 + (B+2)*8 + sdt)*128 + scq);
    if (B < 63) {                          // project batch B+1 -> preLDS[SLOT^1]
      floatx4 accP[4];
#pragma unroll
      for (int g = 0; g < 4; ++g) { float bb = bias_v[g]; accP[g] = (floatx4){bb,bb,bb,bb}; }
#pragma unroll
      for (int kt = 0; kt < 4; ++kt) {
        half8 af = aF[SLOT^1][kt*64 + lane];
#pragma unroll
        for (int g = 0; g < 4; ++g)
          accP[g] = __builtin_amdgcn_mfma_f32_16x16x32_f16(af, bf[kt][g], accP[g], 0, 0, 0);
      }
#pragma unroll
      for (int reg = 0; reg < 4; ++reg) {
        int m = ((lane>>4)<<2) + reg;
        floatx4 pv = (floatx4){accP[0][reg], accP[1][reg], accP[2][reg], accP[3][reg]};
        *reinterpret_cast<floatx4*>(&preLDS[SLOT^1][(m*128 + en)*4]) = pv;
      }
    }
    core(ic<SLOT*8 + 0>{});
    __syncthreads();
    if (B < 62)                            // T14: LDS-write of stashed batch
      *reinterpret_cast<uint2*>(((_Float16*)aF[SLOT]) + sidx) = sv;
    core(ic<SLOT*8 + 1>{});
    __syncthreads(); core(ic<SLOT*8 + 2>{});
    __syncthreads(); core(ic<SLOT*8 + 3>{});
    __syncthreads(); core(ic<SLOT*8 + 4>{});
    __syncthreads(); core(ic<SLOT*8 + 5>{});
    __syncthreads(); core(ic<SLOT*8 + 6>{});
    __syncthreads(); core(ic<SLOT*8 + 7>{});
  };

  for (int bp = 0; bp < 32; ++bp) {
    window(2*bp,     ic<0>{});
    window(2*bp + 1, ic<1>{});
  }

  // fused head: out[r] = sum_n h_last[r][n]*wlin[n] + blin
  if (lane < 32) head[rb*128 + en] = hl * wl;
  __syncthreads();
  if (tid < 2) {
    float s = blin[0];
    for (int n = 0; n < 128; ++n) s += head[tid*128 + n];
    out[r0 + tid] = s;
  }
}

extern "C" void kernel_launch(void* const* d_in, const int* in_sizes, int n_in,
                              void* d_out, int out_size, void* d_ws, size_t ws_size,
                              hipStream_t stream)
{
  const float* x    = (const float*)d_in[0];
  const float* wih0 = (const float*)d_in[1];
  const float* whh0 = (const float*)d_in[2];
  const float* bih0 = (const float*)d_in[3];
  const float* bhh0 = (const float*)d_in[4];
  const float* wih1 = (const float*)d_in[5];
  const float* whh1 = (const float*)d_in[6];
  const float* bih1 = (const float*)d_in[7];
  const float* bhh1 = (const float*)d_in[8];
  const float* wlin = (const float*)d_in[9];
  const float* blin = (const float*)d_in[10];
  float* out = (float*)d_out;

  char* ws = (char*)d_ws;
  _Float16* w0f = (_Float16*)(ws);               // 196608 B
  _Float16* w1f = (_Float16*)(ws + 196608);      // 262144 B
  float* bias0  = (float*)(ws + 458752);         // 2048 B
  float* bias1  = (float*)(ws + 460800);         // 2048 B
  _Float16* h1  = (_Float16*)(ws + 1048576);     // 64 MB inter-layer buffer

  prep_kernel<<<256, 256, 0, stream>>>(wih0, whh0, bih0, bhh0, wih1, whh1, bih1, bhh1,
                                       w0f, w1f, bias0, bias1);
  lstm_l0<<<256, 512, 0, stream>>>(x, w0f, bias0, h1);
  lstm_l1<<<256, 512, 0, stream>>>(h1, w1f, bias1, wlin, blin, out);
}